// Round 1
// baseline (12447.131 us; speedup 1.0000x reference)
//
#include <hip/hip_runtime.h>

#define BB 8
#define CC 64
#define HH 128
#define WW 128
#define TT 3
#define LL 4
#define MM 3

// ---------------------------------------------------------------------------
// Routing: argmax over (a + g) per layer, chained on previous index.
// (log_softmax + g)/tau is a monotone transform of (a + g) since the
// log-sum-exp shift is constant per row and tau > 0.
// ---------------------------------------------------------------------------
__global__ void routing_kernel(const float* __restrict__ alpha0, // [T][1][M]
                               const float* __restrict__ alphas, // [L-1][T][M][M]
                               const float* __restrict__ g0,     // [T][1][M]
                               const float* __restrict__ gs,     // [L-1][T][M][M]
                               int* __restrict__ sel)            // [T][L]
{
    if (blockIdx.x != 0 || threadIdx.x != 0) return;
    for (int t = 0; t < TT; ++t) {
        int idx = 0;
        for (int layer = 0; layer < LL; ++layer) {
            const float* a;
            const float* g;
            if (layer == 0) {
                a = alpha0 + t * MM;
                g = g0 + t * MM;
            } else {
                int off = (((layer - 1) * TT + t) * MM + idx) * MM;
                a = alphas + off;
                g = gs + off;
            }
            float best = a[0] + g[0];
            int bi = 0;
            for (int j = 1; j < MM; ++j) {
                float v = a[j] + g[j];
                if (v > best) { best = v; bi = j; }
            }
            sel[t * LL + layer] = bi;
            idx = bi;
        }
    }
}

// ---------------------------------------------------------------------------
// 3x3 SAME conv + bias + ReLU, C=64 -> C=64, fp32 direct with LDS input tile.
// Block: 256 threads, one 16x16 spatial tile, 32 output channels (ocg 0/1).
// Weights accessed with wave-uniform addresses -> scalar loads (broadcast).
// ---------------------------------------------------------------------------
__global__ __launch_bounds__(256) void conv3x3_relu(
    const float* __restrict__ in,    // [B][C][H][W]
    float* __restrict__ out,         // [B][C][H][W]
    const float* __restrict__ enc_w, // [L][M][C][C][3][3]
    const float* __restrict__ enc_b, // [L][M][C]
    const int* __restrict__ sel,     // [T][L]
    int layer, int task)
{
    const int tile_x = blockIdx.x;          // 0..7
    const int tile_y = blockIdx.y;          // 0..7
    const int b      = blockIdx.z >> 1;     // 0..7
    const int ocg    = blockIdx.z & 1;      // 0..1

    int m = sel[task * LL + layer];
    m = __builtin_amdgcn_readfirstlane(m);

    const float* Wt = enc_w + ((size_t)layer * MM + m) * CC * CC * 9;
    const float* Bt = enc_b + ((size_t)layer * MM + m) * CC;

    const int tx = threadIdx.x & 15;
    const int ty = threadIdx.x >> 4;
    const int ox = tile_x * 16 + tx;
    const int oy = tile_y * 16 + ty;

    __shared__ float smem[8][18][18];

    float acc[32];
#pragma unroll
    for (int i = 0; i < 32; ++i) acc[i] = 0.f;

    const float* inb = in + (size_t)b * CC * HH * WW;

    for (int cc = 0; cc < CC; cc += 8) {
        __syncthreads();  // protect previous chunk's reads
        for (int i = threadIdx.x; i < 8 * 18 * 18; i += 256) {
            int ic = i / (18 * 18);
            int r  = i - ic * (18 * 18);
            int yy = r / 18;
            int xx = r - yy * 18;
            int gy = tile_y * 16 + yy - 1;
            int gx = tile_x * 16 + xx - 1;
            float v = 0.f;
            if (gy >= 0 && gy < HH && gx >= 0 && gx < WW)
                v = inb[(size_t)(cc + ic) * HH * WW + (size_t)gy * WW + gx];
            smem[ic][yy][xx] = v;
        }
        __syncthreads();

#pragma unroll
        for (int ic = 0; ic < 8; ++ic) {
            float i00 = smem[ic][ty + 0][tx + 0];
            float i01 = smem[ic][ty + 0][tx + 1];
            float i02 = smem[ic][ty + 0][tx + 2];
            float i10 = smem[ic][ty + 1][tx + 0];
            float i11 = smem[ic][ty + 1][tx + 1];
            float i12 = smem[ic][ty + 1][tx + 2];
            float i20 = smem[ic][ty + 2][tx + 0];
            float i21 = smem[ic][ty + 2][tx + 1];
            float i22 = smem[ic][ty + 2][tx + 2];
            const float* wic = Wt + (size_t)(cc + ic) * 9;
#pragma unroll
            for (int oc = 0; oc < 32; ++oc) {
                const float* w = wic + (size_t)(ocg * 32 + oc) * (CC * 9);
                acc[oc] += i00 * w[0] + i01 * w[1] + i02 * w[2]
                         + i10 * w[3] + i11 * w[4] + i12 * w[5]
                         + i20 * w[6] + i21 * w[7] + i22 * w[8];
            }
        }
    }

    float* outb = out + (size_t)b * CC * HH * WW + (size_t)oy * WW + ox;
#pragma unroll
    for (int oc = 0; oc < 32; ++oc) {
        int oc_g = ocg * 32 + oc;
        float v = acc[oc] + Bt[oc_g];
        outb[(size_t)oc_g * HH * WW] = fmaxf(v, 0.f);
    }
}

// ---------------------------------------------------------------------------
// Decoder: 1x1 conv 64 -> 3 (+bias), optional L2-normalize over the 3 chans.
// One thread per (b, y, x).
// ---------------------------------------------------------------------------
__global__ __launch_bounds__(256) void decoder_kernel(
    const float* __restrict__ h,     // [B][64][H][W]
    const float* __restrict__ dec_w, // [T][3][64]
    const float* __restrict__ dec_b, // [T][3]
    float* __restrict__ out,         // [T][B][3][H][W]
    int task, int normalize)
{
    const int HW = HH * WW;
    int idx = blockIdx.x * blockDim.x + threadIdx.x;
    if (idx >= BB * HW) return;
    int b = idx / HW;
    int p = idx - b * HW;

    const float* hb = h + (size_t)b * CC * HW + p;
    const float* w  = dec_w + (size_t)task * 3 * CC;

    float a0 = dec_b[task * 3 + 0];
    float a1 = dec_b[task * 3 + 1];
    float a2 = dec_b[task * 3 + 2];
#pragma unroll 8
    for (int ic = 0; ic < CC; ++ic) {
        float v = hb[(size_t)ic * HW];
        a0 += v * w[ic];
        a1 += v * w[CC + ic];
        a2 += v * w[2 * CC + ic];
    }
    if (normalize) {
        float nrm = sqrtf(a0 * a0 + a1 * a1 + a2 * a2);
        float r = 1.0f / nrm;
        a0 *= r; a1 *= r; a2 *= r;
    }
    float* ob = out + ((size_t)task * BB + b) * 3 * HW + p;
    ob[0]      = a0;
    ob[HW]     = a1;
    ob[2 * HW] = a2;
}

extern "C" void kernel_launch(void* const* d_in, const int* in_sizes, int n_in,
                              void* d_out, int out_size, void* d_ws, size_t ws_size,
                              hipStream_t stream) {
    const float* x      = (const float*)d_in[0];
    const float* alpha0 = (const float*)d_in[1];
    const float* alphas = (const float*)d_in[2];
    const float* g0     = (const float*)d_in[3];
    const float* gs     = (const float*)d_in[4];
    const float* enc_w  = (const float*)d_in[5];
    const float* enc_b  = (const float*)d_in[6];
    const float* dec_w  = (const float*)d_in[7];
    const float* dec_b  = (const float*)d_in[8];
    float* out = (float*)d_out;

    int* sel = (int*)d_ws;
    float* bufA = (float*)((char*)d_ws + 1024);
    float* bufB = bufA + (size_t)BB * CC * HH * WW;

    routing_kernel<<<1, 64, 0, stream>>>(alpha0, alphas, g0, gs, sel);

    for (int t = 0; t < TT; ++t) {
        conv3x3_relu<<<dim3(8, 8, 16), 256, 0, stream>>>(x,    bufA, enc_w, enc_b, sel, 0, t);
        conv3x3_relu<<<dim3(8, 8, 16), 256, 0, stream>>>(bufA, bufB, enc_w, enc_b, sel, 1, t);
        conv3x3_relu<<<dim3(8, 8, 16), 256, 0, stream>>>(bufB, bufA, enc_w, enc_b, sel, 2, t);
        conv3x3_relu<<<dim3(8, 8, 16), 256, 0, stream>>>(bufA, bufB, enc_w, enc_b, sel, 3, t);
        decoder_kernel<<<(BB * HH * WW + 255) / 256, 256, 0, stream>>>(
            bufB, dec_w, dec_b, out, t, t == 2 ? 1 : 0);
    }
}

// Round 2
// 852.034 us; speedup vs baseline: 14.6087x; 14.6087x over previous
//
#include <hip/hip_runtime.h>

#define BB 8
#define CC 64
#define HH 128
#define WW 128
#define TT 3
#define LL 4
#define MM 3

typedef _Float16 half8 __attribute__((ext_vector_type(8)));
typedef float floatx16 __attribute__((ext_vector_type(16)));

// ---------------------------------------------------------------------------
// Routing: argmax over (a + g) per layer, chained on previous index.
// (log_softmax(a) + g)/tau is a monotone transform of (a + g).
// ---------------------------------------------------------------------------
__global__ void routing_kernel(const float* __restrict__ alpha0, // [T][1][M]
                               const float* __restrict__ alphas, // [L-1][T][M][M]
                               const float* __restrict__ g0,     // [T][1][M]
                               const float* __restrict__ gs,     // [L-1][T][M][M]
                               int* __restrict__ sel)            // [T][L]
{
    if (blockIdx.x != 0 || threadIdx.x != 0) return;
    for (int t = 0; t < TT; ++t) {
        int idx = 0;
        for (int layer = 0; layer < LL; ++layer) {
            const float* a;
            const float* g;
            if (layer == 0) {
                a = alpha0 + t * MM;
                g = g0 + t * MM;
            } else {
                int off = (((layer - 1) * TT + t) * MM + idx) * MM;
                a = alphas + off;
                g = gs + off;
            }
            float best = a[0] + g[0];
            int bi = 0;
            for (int j = 1; j < MM; ++j) {
                float v = a[j] + g[j];
                if (v > best) { best = v; bi = j; }
            }
            sel[t * LL + layer] = bi;
            idx = bi;
        }
    }
}

// ---------------------------------------------------------------------------
// Weight prep: gather selected modules, fp32 -> fp16, transpose OIHW ->
// [tl=t*4+layer][tap][oc][ic] so conv A-frags are ic-contiguous 16B loads.
// ---------------------------------------------------------------------------
__global__ __launch_bounds__(256) void prep_weights(
    const float* __restrict__ enc_w, // [L][M][64][64][3][3]
    const int* __restrict__ sel,     // [T][L]
    _Float16* __restrict__ W2)       // [12][9][64][64]
{
    int tl = blockIdx.y;             // 0..11
    int t = tl >> 2, layer = tl & 3;
    int m = sel[t * LL + layer];
    const float* src = enc_w + ((size_t)layer * MM + m) * (CC * CC * 9);
    _Float16* dst = W2 + (size_t)tl * 9 * CC * CC;
    for (int i = blockIdx.x * 256 + threadIdx.x; i < CC * CC * 9; i += gridDim.x * 256) {
        // src index: oc*576 + ic*9 + tap
        int oc = i / 576;
        int r = i - oc * 576;
        int ic = r / 9;
        int tap = r - ic * 9;
        dst[(size_t)tap * (CC * CC) + oc * CC + ic] = (_Float16)src[i];
    }
}

// ---------------------------------------------------------------------------
// 3x3 SAME conv + bias + ReLU via fp16 MFMA implicit GEMM.
// Block = 256 thr (4 waves) computes one output row: 64 oc x 128 px.
// LDS: input tile [3 rows][130 cols][72 ic-pad] f16 (stride 144B = full-BW
// for stride-1-lane ds_read_b128). Weights: 36 A-frags in registers.
// wave w: oc_half = w&1 (32 oc), px_half = w>>1 (64 px = 2 MFMA N-tiles).
// ---------------------------------------------------------------------------
__global__ __launch_bounds__(256, 1) void conv3x3_mfma(
    const float* __restrict__ in,    // [B][64][128][128] fp32
    float* __restrict__ out,         // [B][64][128][128] fp32
    const _Float16* __restrict__ W2, // [12][9][64][64] f16
    const float* __restrict__ enc_b, // [L][M][64]
    const int* __restrict__ sel,     // [T][L]
    int layer, int task)
{
    const int y   = blockIdx.x;   // output row
    const int b   = blockIdx.y;
    const int tid = threadIdx.x;
    const int lane = tid & 63;
    const int wave = tid >> 6;
    const int oc_half = wave & 1;
    const int px_half = wave >> 1;

    __shared__ __align__(16) _Float16 lds[3 * 130 * 72];

    // ---- A-frags: 9 taps x 4 ic-chunks, held in registers ----
    const int tl = task * LL + layer;
    const _Float16* Wtl = W2 + (size_t)tl * 9 * CC * CC;
    half8 afrag[36];
#pragma unroll
    for (int tap = 0; tap < 9; ++tap) {
#pragma unroll
        for (int icc = 0; icc < 4; ++icc) {
            const _Float16* p = Wtl + (size_t)tap * (CC * CC)
                              + (oc_half * 32 + (lane & 31)) * CC
                              + icc * 16 + (lane >> 5) * 8;
            afrag[tap * 4 + icc] = *(const half8*)p;
        }
    }

    // ---- stage input tile: 3 rows x 130 cols x 64 ic, fp32->f16 ----
    const float* inb = in + (size_t)b * (CC * HH * WW);
    for (int i = tid; i < 32 * 390; i += 256) {
        int icp = i / 390;            // ic pair 0..31
        int rem = i - icp * 390;
        int r = rem / 130;            // 0..2
        int c = rem - r * 130;        // 0..129
        int gy = y + r - 1;
        int gx = c - 1;
        float v0 = 0.f, v1 = 0.f;
        if (gy >= 0 && gy < HH && gx >= 0 && gx < WW) {
            const float* p = inb + ((size_t)(2 * icp) * HH + gy) * WW + gx;
            v0 = p[0];
            v1 = p[HH * WW];
        }
        union { _Float16 h[2]; unsigned u; } pk;
        pk.h[0] = (_Float16)v0;
        pk.h[1] = (_Float16)v1;
        *(unsigned*)&lds[(r * 130 + c) * 72 + 2 * icp] = pk.u;
    }
    __syncthreads();

    // ---- K-loop: 9 taps x 4 ic-chunks of K=16 ----
    floatx16 acc0, acc1;
#pragma unroll
    for (int i = 0; i < 16; ++i) { acc0[i] = 0.f; acc1[i] = 0.f; }

    const int xbase = px_half * 64 + (lane & 31);
    const int krow  = (lane >> 5) * 8;
#pragma unroll
    for (int tap = 0; tap < 9; ++tap) {
        const int dy = tap / 3;
        const int dx = tap - dy * 3;
        const _Float16* base = &lds[((dy * 130) + xbase + dx) * 72 + krow];
#pragma unroll
        for (int icc = 0; icc < 4; ++icc) {
            half8 b0 = *(const half8*)(base + icc * 16);
            half8 b1 = *(const half8*)(base + 32 * 72 + icc * 16);
            acc0 = __builtin_amdgcn_mfma_f32_32x32x16_f16(afrag[tap * 4 + icc], b0, acc0, 0, 0, 0);
            acc1 = __builtin_amdgcn_mfma_f32_32x32x16_f16(afrag[tap * 4 + icc], b1, acc1, 0, 0, 0);
        }
    }

    // ---- epilogue: bias + ReLU, store fp32 ----
    int m = sel[task * LL + layer];
    m = __builtin_amdgcn_readfirstlane(m);
    const float* Bp = enc_b + ((size_t)layer * MM + m) * CC;
    float* outb = out + (size_t)b * (CC * HH * WW) + (size_t)y * WW;
    const int col = lane & 31;
#pragma unroll
    for (int reg = 0; reg < 16; ++reg) {
        int row = (reg & 3) + 8 * (reg >> 2) + 4 * (lane >> 5);
        int oc = oc_half * 32 + row;
        float bias = Bp[oc];
        float* po = outb + (size_t)oc * (HH * WW) + px_half * 64 + col;
        po[0]  = fmaxf(acc0[reg] + bias, 0.f);
        po[32] = fmaxf(acc1[reg] + bias, 0.f);
    }
}

// ---------------------------------------------------------------------------
// Decoder: 1x1 conv 64 -> 3 (+bias), optional L2-normalize over the 3 chans.
// ---------------------------------------------------------------------------
__global__ __launch_bounds__(256) void decoder_kernel(
    const float* __restrict__ h,     // [B][64][H][W]
    const float* __restrict__ dec_w, // [T][3][64]
    const float* __restrict__ dec_b, // [T][3]
    float* __restrict__ out,         // [T][B][3][H][W]
    int task, int normalize)
{
    const int HW = HH * WW;
    int idx = blockIdx.x * blockDim.x + threadIdx.x;
    if (idx >= BB * HW) return;
    int b = idx / HW;
    int p = idx - b * HW;

    const float* hb = h + (size_t)b * CC * HW + p;
    const float* w  = dec_w + (size_t)task * 3 * CC;

    float a0 = dec_b[task * 3 + 0];
    float a1 = dec_b[task * 3 + 1];
    float a2 = dec_b[task * 3 + 2];
#pragma unroll 8
    for (int ic = 0; ic < CC; ++ic) {
        float v = hb[(size_t)ic * HW];
        a0 += v * w[ic];
        a1 += v * w[CC + ic];
        a2 += v * w[2 * CC + ic];
    }
    if (normalize) {
        float nrm = sqrtf(a0 * a0 + a1 * a1 + a2 * a2);
        float r = 1.0f / nrm;
        a0 *= r; a1 *= r; a2 *= r;
    }
    float* ob = out + ((size_t)task * BB + b) * 3 * HW + p;
    ob[0]      = a0;
    ob[HW]     = a1;
    ob[2 * HW] = a2;
}

extern "C" void kernel_launch(void* const* d_in, const int* in_sizes, int n_in,
                              void* d_out, int out_size, void* d_ws, size_t ws_size,
                              hipStream_t stream) {
    const float* x      = (const float*)d_in[0];
    const float* alpha0 = (const float*)d_in[1];
    const float* alphas = (const float*)d_in[2];
    const float* g0     = (const float*)d_in[3];
    const float* gs     = (const float*)d_in[4];
    const float* enc_w  = (const float*)d_in[5];
    const float* enc_b  = (const float*)d_in[6];
    const float* dec_w  = (const float*)d_in[7];
    const float* dec_b  = (const float*)d_in[8];
    float* out = (float*)d_out;

    int* sel = (int*)d_ws;
    _Float16* W2 = (_Float16*)((char*)d_ws + 1024);                // 12*9*64*64*2 = 884736 B
    float* bufA = (float*)((char*)d_ws + 1024 + 884736);
    float* bufB = bufA + (size_t)BB * CC * HH * WW;

    routing_kernel<<<1, 64, 0, stream>>>(alpha0, alphas, g0, gs, sel);
    prep_weights<<<dim3(36, 12), 256, 0, stream>>>(enc_w, sel, W2);

    for (int t = 0; t < TT; ++t) {
        conv3x3_mfma<<<dim3(HH, BB), 256, 0, stream>>>(x,    bufA, W2, enc_b, sel, 0, t);
        conv3x3_mfma<<<dim3(HH, BB), 256, 0, stream>>>(bufA, bufB, W2, enc_b, sel, 1, t);
        conv3x3_mfma<<<dim3(HH, BB), 256, 0, stream>>>(bufB, bufA, W2, enc_b, sel, 2, t);
        conv3x3_mfma<<<dim3(HH, BB), 256, 0, stream>>>(bufA, bufB, W2, enc_b, sel, 3, t);
        decoder_kernel<<<(BB * HH * WW + 255) / 256, 256, 0, stream>>>(
            bufB, dec_w, dec_b, out, t, t == 2 ? 1 : 0);
    }
}

// Round 3
// 457.407 us; speedup vs baseline: 27.2124x; 1.8627x over previous
//
#include <hip/hip_runtime.h>

#define BB 8
#define CC 64
#define HH 128
#define WW 128
#define TT 3
#define LL 4
#define MM 3
#define PADH 40                  // halves per px in conv LDS tile (32 ch + 8 pad) -> 80B stride

typedef _Float16 half8 __attribute__((ext_vector_type(8)));
typedef _Float16 half4 __attribute__((ext_vector_type(4)));
typedef float floatx16 __attribute__((ext_vector_type(16)));

// ---------------------------------------------------------------------------
// Routing: argmax over (a + g), chained on previous index.
// ---------------------------------------------------------------------------
__global__ void routing_kernel(const float* __restrict__ alpha0,
                               const float* __restrict__ alphas,
                               const float* __restrict__ g0,
                               const float* __restrict__ gs,
                               int* __restrict__ sel) // [T][L]
{
    if (blockIdx.x != 0 || threadIdx.x != 0) return;
    for (int t = 0; t < TT; ++t) {
        int idx = 0;
        for (int layer = 0; layer < LL; ++layer) {
            const float *a, *g;
            if (layer == 0) { a = alpha0 + t * MM; g = g0 + t * MM; }
            else {
                int off = (((layer - 1) * TT + t) * MM + idx) * MM;
                a = alphas + off; g = gs + off;
            }
            float best = a[0] + g[0];
            int bi = 0;
            for (int j = 1; j < MM; ++j) {
                float v = a[j] + g[j];
                if (v > best) { best = v; bi = j; }
            }
            sel[t * LL + layer] = bi;
            idx = bi;
        }
    }
}

// ---------------------------------------------------------------------------
// Weight prep: gather selected modules, fp32 -> fp16, OIHW -> [tl][tap][oc][ic]
// ---------------------------------------------------------------------------
__global__ __launch_bounds__(256) void prep_weights(
    const float* __restrict__ enc_w, // [L][M][64][64][3][3]
    const int* __restrict__ sel,
    _Float16* __restrict__ W2)       // [12][9][64][64]
{
    int tl = blockIdx.y;
    int t = tl >> 2, layer = tl & 3;
    int m = sel[t * LL + layer];
    const float* src = enc_w + ((size_t)layer * MM + m) * (CC * CC * 9);
    _Float16* dst = W2 + (size_t)tl * 9 * CC * CC;
    for (int i = blockIdx.x * 256 + threadIdx.x; i < CC * CC * 9; i += gridDim.x * 256) {
        int oc = i / 576;
        int r = i - oc * 576;
        int ic = r / 9;
        int tap = r - ic * 9;
        dst[(size_t)tap * (CC * CC) + oc * CC + ic] = (_Float16)src[i];
    }
}

// ---------------------------------------------------------------------------
// x: NCHW fp32 -> NHWC f16 (act0). Block: 64 px x 64 ch, LDS transpose.
// ---------------------------------------------------------------------------
__global__ __launch_bounds__(256) void to_nhwc(
    const float* __restrict__ x,    // [B][64][128][128]
    _Float16* __restrict__ act0)    // [B][128][128][64]
{
    const int xs = blockIdx.x;  // 0..1
    const int y  = blockIdx.y;  // 0..127
    const int b  = blockIdx.z;  // 0..7

    __shared__ _Float16 lds[64 * 72];  // [px][ch], pad 72

    int ch = threadIdx.x >> 4;      // 0..15? no: 256 thr: tid>>4 = 0..15 -> need 64 ch
    // thread mapping: ch = tid >> 2? We need 64ch x 16 x4px chunks = 256 threads:
    // t = ch*4 + xq : ch 0..63, xq 0..3 (16 px each... 4 px per load -> 4 loads of 4px? )
    // simpler: ch = tid >> 2 (0..63), xq = tid & 3 (each loads 16 px = 4 x float4)
    ch = threadIdx.x >> 2;
    int xq = threadIdx.x & 3;
    const float* src = x + (((size_t)b * CC + ch) * HH + y) * WW + xs * 64 + xq * 16;
#pragma unroll
    for (int k = 0; k < 4; ++k) {
        float4 v = *(const float4*)(src + k * 4);
        int px = xq * 16 + k * 4;
        lds[(px + 0) * 72 + ch] = (_Float16)v.x;
        lds[(px + 1) * 72 + ch] = (_Float16)v.y;
        lds[(px + 2) * 72 + ch] = (_Float16)v.z;
        lds[(px + 3) * 72 + ch] = (_Float16)v.w;
    }
    __syncthreads();
    // write out: t: px = tid>>2, q = tid&3 -> 16 halves (32B)
    int px = threadIdx.x >> 2;
    int q  = threadIdx.x & 3;
    _Float16* dst = act0 + (((size_t)b * HH + y) * WW + xs * 64 + px) * CC + q * 16;
    half8 h0 = *(const half8*)&lds[px * 72 + q * 16];
    half8 h1 = *(const half8*)&lds[px * 72 + q * 16 + 8];
    *(half8*)dst = h0;
    *(half8*)(dst + 8) = h1;
}

// ---------------------------------------------------------------------------
// 3x3 SAME conv + bias + ReLU, NHWC f16 -> NHWC f16, MFMA 32x32x16.
// Block 256 thr / 4 waves: 2 output rows x 128 px x 64 oc.
// Wave (rsel = w&1, p = w>>1): 1 row x 64 px (2 n-tiles) x 64 oc (2 m-tiles).
// LDS: input [4 rows][130 px][PADH] halves, 32-ch chunks (2 passes).
// Weights: per-(chunk,tap) register prefetch (4 frags), double buffered.
// ---------------------------------------------------------------------------
__global__ __launch_bounds__(256, 2) void conv3x3_mfma(
    const _Float16* __restrict__ in,   // NHWC per task (stride tsi halves)
    _Float16* __restrict__ out,        // NHWC per task (stride tso halves)
    const _Float16* __restrict__ W2,   // [12][9][64][64]
    const float* __restrict__ enc_b,   // [L][M][64]
    const int* __restrict__ sel,
    int layer, int task0, size_t tsi, size_t tso)
{
    const int y0 = blockIdx.x * 2;
    const int b  = blockIdx.y;
    const int tz = blockIdx.z;
    const int t  = task0 + tz;

    const _Float16* inp = in + (size_t)tz * tsi + (size_t)b * (HH * WW * CC);
    _Float16* outp      = out + (size_t)tz * tso + (size_t)b * (HH * WW * CC);
    const int tl = t * LL + layer;
    const _Float16* Wt = W2 + (size_t)tl * 9 * CC * CC;

    const int tid  = threadIdx.x;
    const int lane = tid & 63;
    const int wave = tid >> 6;
    const int rsel = wave & 1;
    const int p    = wave >> 1;
    const int n    = lane & 31;
    const int ksub = lane >> 5;

    __shared__ __align__(16) _Float16 lds[4 * 130 * PADH]; // 41,600 B

    floatx16 acc[2][2];
#pragma unroll
    for (int o = 0; o < 2; ++o)
#pragma unroll
        for (int j = 0; j < 2; ++j)
#pragma unroll
            for (int i = 0; i < 16; ++i) acc[o][j][i] = 0.f;

    half8 a_cur[2][2], a_nxt[2][2];  // [o][il]

    // W frag half-offset: tap*4096 + (o*32+n)*64 + c*32 + il*16 + ksub*8
#define WFRAG(c, tap, o, il) \
    (*(const half8*)(Wt + (tap) * 4096 + ((o) * 32 + n) * 64 + (c) * 32 + (il) * 16 + ksub * 8))

#pragma unroll
    for (int o = 0; o < 2; ++o)
#pragma unroll
        for (int il = 0; il < 2; ++il) a_cur[o][il] = WFRAG(0, 0, o, il);

    for (int c = 0; c < 2; ++c) {
        if (c) __syncthreads();   // all reads of chunk 0 done
        // ---- stage input chunk: 4 rows x 130 px x 32 ch ----
        for (int i = tid; i < 2080; i += 256) {
            int r = i / 520;
            int rem = i - r * 520;
            int px = rem >> 2;
            int c8 = rem & 3;
            int gy = y0 - 1 + r;
            int gx = px - 1;
            half8 v = {};
            if ((unsigned)gy < HH && (unsigned)gx < WW)
                v = *(const half8*)(inp + ((size_t)gy * WW + gx) * CC + c * 32 + c8 * 8);
            *(half8*)&lds[(r * 130 + px) * PADH + c8 * 8] = v;
        }
        __syncthreads();

#pragma unroll
        for (int tap = 0; tap < 9; ++tap) {
            // prefetch next (c,tap) weight frags
            int nc = (tap == 8) ? c + 1 : c;
            int ntap = (tap == 8) ? 0 : tap + 1;
            if (nc < 2) {
#pragma unroll
                for (int o = 0; o < 2; ++o)
#pragma unroll
                    for (int il = 0; il < 2; ++il) a_nxt[o][il] = WFRAG(nc, ntap, o, il);
            }
            const int dy = tap / 3;
            const int dx = tap - dy * 3;
            const int rbase = (rsel + dy) * 130 + p * 64 + dx;
#pragma unroll
            for (int il = 0; il < 2; ++il) {
                const int koff = il * 16 + ksub * 8;
                half8 b0 = *(const half8*)&lds[(rbase + n) * PADH + koff];
                half8 b1 = *(const half8*)&lds[(rbase + 32 + n) * PADH + koff];
                acc[0][0] = __builtin_amdgcn_mfma_f32_32x32x16_f16(a_cur[0][il], b0, acc[0][0], 0, 0, 0);
                acc[0][1] = __builtin_amdgcn_mfma_f32_32x32x16_f16(a_cur[0][il], b1, acc[0][1], 0, 0, 0);
                acc[1][0] = __builtin_amdgcn_mfma_f32_32x32x16_f16(a_cur[1][il], b0, acc[1][0], 0, 0, 0);
                acc[1][1] = __builtin_amdgcn_mfma_f32_32x32x16_f16(a_cur[1][il], b1, acc[1][1], 0, 0, 0);
            }
#pragma unroll
            for (int o = 0; o < 2; ++o)
#pragma unroll
                for (int il = 0; il < 2; ++il) a_cur[o][il] = a_nxt[o][il];
        }
    }
#undef WFRAG

    // ---- epilogue: bias + ReLU -> NHWC f16 ----
    int m = sel[t * LL + layer];
    m = __builtin_amdgcn_readfirstlane(m);
    const float* Bp = enc_b + ((size_t)layer * MM + m) * CC;
    _Float16* orow = outp + (size_t)(y0 + rsel) * WW * CC;
#pragma unroll
    for (int o = 0; o < 2; ++o)
#pragma unroll
        for (int j = 0; j < 2; ++j) {
            int px = p * 64 + j * 32 + n;
            _Float16* po = orow + (size_t)px * CC;
#pragma unroll
            for (int rg = 0; rg < 4; ++rg) {
                int oc = o * 32 + 4 * ksub + 8 * rg;
                half4 h;
#pragma unroll
                for (int k = 0; k < 4; ++k)
                    h[k] = (_Float16)fmaxf(acc[o][j][rg * 4 + k] + Bp[oc + k], 0.f);
                *(half4*)(po + oc) = h;
            }
        }
}

// ---------------------------------------------------------------------------
// Decoder: 1x1 conv 64 -> 3 (+bias), L2-normalize for task 2. NHWC f16 input.
// ---------------------------------------------------------------------------
__global__ __launch_bounds__(256) void decoder_kernel(
    const _Float16* __restrict__ in, // NHWC f16, per-task stride ts halves
    size_t ts,
    const float* __restrict__ dec_w, // [T][3][64]
    const float* __restrict__ dec_b, // [T][3]
    float* __restrict__ out,         // [T][B][3][H][W]
    int task0, int ntask)
{
    const int HW = HH * WW;
    int gid = blockIdx.x * 256 + threadIdx.x;
    if (gid >= ntask * BB * HW) return;
    int tz = gid / (BB * HW);
    int rem = gid - tz * (BB * HW);
    int b = rem / HW;
    int px = rem - b * HW;
    int t = task0 + tz;

    const _Float16* hp = in + (size_t)tz * ts + ((size_t)b * HW + px) * CC;
    const float* w = dec_w + (size_t)t * 3 * CC;

    float a0 = dec_b[t * 3 + 0];
    float a1 = dec_b[t * 3 + 1];
    float a2 = dec_b[t * 3 + 2];
#pragma unroll
    for (int cc = 0; cc < CC; cc += 8) {
        half8 h = *(const half8*)(hp + cc);
#pragma unroll
        for (int k = 0; k < 8; ++k) {
            float v = (float)h[k];
            a0 += v * w[cc + k];
            a1 += v * w[CC + cc + k];
            a2 += v * w[2 * CC + cc + k];
        }
    }
    if (t == 2) {
        float r = 1.0f / sqrtf(a0 * a0 + a1 * a1 + a2 * a2);
        a0 *= r; a1 *= r; a2 *= r;
    }
    float* ob = out + ((size_t)t * BB + b) * 3 * HW + px;
    ob[0]      = a0;
    ob[HW]     = a1;
    ob[2 * HW] = a2;
}

extern "C" void kernel_launch(void* const* d_in, const int* in_sizes, int n_in,
                              void* d_out, int out_size, void* d_ws, size_t ws_size,
                              hipStream_t stream) {
    const float* x      = (const float*)d_in[0];
    const float* alpha0 = (const float*)d_in[1];
    const float* alphas = (const float*)d_in[2];
    const float* g0     = (const float*)d_in[3];
    const float* gs     = (const float*)d_in[4];
    const float* enc_w  = (const float*)d_in[5];
    const float* enc_b  = (const float*)d_in[6];
    const float* dec_w  = (const float*)d_in[7];
    const float* dec_b  = (const float*)d_in[8];
    float* out = (float*)d_out;

    const size_t ACT = (size_t)BB * HH * WW * CC;      // halves per activation buffer
    char* pw = (char*)d_ws;
    int* sel = (int*)pw;                 pw += 1024;
    _Float16* W2 = (_Float16*)pw;        pw += (size_t)12 * 9 * CC * CC * 2;
    _Float16* act0 = (_Float16*)pw;      pw += ACT * 2;
    _Float16* bufs = (_Float16*)pw;
    size_t base = (size_t)(pw - (char*)d_ws);
    bool fused = ws_size >= base + 6 * ACT * 2;

    routing_kernel<<<1, 64, 0, stream>>>(alpha0, alphas, g0, gs, sel);
    prep_weights<<<dim3(36, 12), 256, 0, stream>>>(enc_w, sel, W2);
    to_nhwc<<<dim3(2, HH, BB), 256, 0, stream>>>(x, act0);

    if (fused) {
        _Float16* A = bufs;        // task stride 2*ACT
        _Float16* B = bufs + ACT;  // task stride 2*ACT
        size_t ts = 2 * ACT;
        conv3x3_mfma<<<dim3(64, BB, 3), 256, 0, stream>>>(act0, A, W2, enc_b, sel, 0, 0, 0,  ts);
        conv3x3_mfma<<<dim3(64, BB, 3), 256, 0, stream>>>(A,    B, W2, enc_b, sel, 1, 0, ts, ts);
        conv3x3_mfma<<<dim3(64, BB, 3), 256, 0, stream>>>(B,    A, W2, enc_b, sel, 2, 0, ts, ts);
        conv3x3_mfma<<<dim3(64, BB, 3), 256, 0, stream>>>(A,    B, W2, enc_b, sel, 3, 0, ts, ts);
        decoder_kernel<<<(3 * BB * HH * WW + 255) / 256, 256, 0, stream>>>(
            B, ts, dec_w, dec_b, out, 0, 3);
    } else {
        _Float16* A = bufs;
        _Float16* B = bufs + ACT;
        for (int t = 0; t < TT; ++t) {
            conv3x3_mfma<<<dim3(64, BB, 1), 256, 0, stream>>>(act0, A, W2, enc_b, sel, 0, t, 0, 0);
            conv3x3_mfma<<<dim3(64, BB, 1), 256, 0, stream>>>(A,    B, W2, enc_b, sel, 1, t, 0, 0);
            conv3x3_mfma<<<dim3(64, BB, 1), 256, 0, stream>>>(B,    A, W2, enc_b, sel, 2, t, 0, 0);
            conv3x3_mfma<<<dim3(64, BB, 1), 256, 0, stream>>>(A,    B, W2, enc_b, sel, 3, t, 0, 0);
            decoder_kernel<<<(BB * HH * WW + 255) / 256, 256, 0, stream>>>(
                B, 0, dec_w, dec_b, out, t, 1);
        }
    }
}

// Round 4
// 321.799 us; speedup vs baseline: 38.6799x; 1.4214x over previous
//
#include <hip/hip_runtime.h>

#define BB 8
#define CC 64
#define HH 128
#define WW 128
#define TT 3
#define LL 4
#define MM 3
#define PADH 40   // halves per px in conv LDS tile (32 ch + 8 pad) -> 80 B stride

typedef _Float16 half8 __attribute__((ext_vector_type(8)));
typedef _Float16 half4 __attribute__((ext_vector_type(4)));
typedef float floatx16 __attribute__((ext_vector_type(16)));

// ---------------------------------------------------------------------------
// Routing: argmax over (a + g), chained on previous index.
// ---------------------------------------------------------------------------
__global__ void routing_kernel(const float* __restrict__ alpha0,
                               const float* __restrict__ alphas,
                               const float* __restrict__ g0,
                               const float* __restrict__ gs,
                               int* __restrict__ sel) // [T][L]
{
    if (blockIdx.x != 0 || threadIdx.x != 0) return;
    for (int t = 0; t < TT; ++t) {
        int idx = 0;
        for (int layer = 0; layer < LL; ++layer) {
            const float *a, *g;
            if (layer == 0) { a = alpha0 + t * MM; g = g0 + t * MM; }
            else {
                int off = (((layer - 1) * TT + t) * MM + idx) * MM;
                a = alphas + off; g = gs + off;
            }
            float best = a[0] + g[0];
            int bi = 0;
            for (int j = 1; j < MM; ++j) {
                float v = a[j] + g[j];
                if (v > best) { best = v; bi = j; }
            }
            sel[t * LL + layer] = bi;
            idx = bi;
        }
    }
}

// ---------------------------------------------------------------------------
// Weight prep: gather selected modules, fp32 -> fp16, rearrange to A-frag
// order: W3[tl][tap][c(2)][il(2)][o(2)][lane(64)*8] -- one a-frag = one
// contiguous 1 KB wave-load.  i = tap*4096 + c*2048 + il*1024 + o*512 + l*8 + j
// ---------------------------------------------------------------------------
__global__ __launch_bounds__(256) void prep_weights(
    const float* __restrict__ enc_w, // [L][M][64][64][3][3]
    const int* __restrict__ sel,
    _Float16* __restrict__ W3)       // [12][36864]
{
    int tl = blockIdx.y;
    int t = tl >> 2, layer = tl & 3;
    int m = sel[t * LL + layer];
    const float* src = enc_w + ((size_t)layer * MM + m) * (CC * CC * 9);
    _Float16* dst = W3 + (size_t)tl * 36864;
    for (int i = blockIdx.x * 256 + threadIdx.x; i < 36864; i += gridDim.x * 256) {
        int j   = i & 7;
        int l   = (i >> 3) & 63;
        int o   = (i >> 9) & 1;
        int il  = (i >> 10) & 1;
        int c   = (i >> 11) & 1;
        int tap = i >> 12;                      // 0..8
        int oc  = o * 32 + (l & 31);
        int kch = c * 32 + il * 16 + (l >> 5) * 8 + j;
        dst[i] = (_Float16)src[(oc * CC + kch) * 9 + tap];
    }
}

// ---------------------------------------------------------------------------
// x: NCHW fp32 -> NHWC f16. Lane = px (coalesced 256 B loads), LDS transpose.
// ---------------------------------------------------------------------------
__global__ __launch_bounds__(256) void to_nhwc(
    const float* __restrict__ x,    // [B][64][128][128]
    _Float16* __restrict__ act0)    // [B][128][128][64]
{
    const int xs = blockIdx.x;  // 0..1
    const int y  = blockIdx.y;  // 0..127
    const int b  = blockIdx.z;  // 0..7

    __shared__ _Float16 lds[64 * 72];  // [px][ch], pad 72

    const int wv = threadIdx.x >> 6;
    const int l  = threadIdx.x & 63;
    const float* src = x + ((size_t)b * CC * HH + y) * WW + xs * 64 + l;
#pragma unroll
    for (int k = 0; k < 16; ++k) {
        int ch = wv * 16 + k;
        lds[l * 72 + ch] = (_Float16)src[(size_t)ch * HH * WW];
    }
    __syncthreads();
    int px = threadIdx.x >> 2;
    int q  = threadIdx.x & 3;
    _Float16* dst = act0 + (((size_t)b * HH + y) * WW + xs * 64 + px) * CC + q * 16;
    *(half8*)dst       = *(const half8*)&lds[px * 72 + q * 16];
    *(half8*)(dst + 8) = *(const half8*)&lds[px * 72 + q * 16 + 8];
}

// ---------------------------------------------------------------------------
// 3x3 SAME conv + bias + ReLU, NHWC f16 -> NHWC f16, MFMA 32x32x16.
// Block 256 thr / 4 waves: 4 output rows x 64 px x 64 oc (wave = one row).
// Per wave: 2 m-tiles(oc) x 2 n-tiles(px) -> acc 4x16, 144 MFMA.
// LDS: input [6 rows][66 px][PADH] halves, 32-ch chunks (2 passes), 31.7 KB.
// Weights: contiguous a-frag loads from W3, double-buffered per (chunk,tap).
// ---------------------------------------------------------------------------
__global__ __launch_bounds__(256, 3) void conv3x3_mfma(
    const _Float16* __restrict__ in,   // NHWC per task (stride tsi halves)
    _Float16* __restrict__ out,        // NHWC per task (stride tso halves)
    const _Float16* __restrict__ W3,   // [12][36864]
    const float* __restrict__ enc_b,   // [L][M][64]
    const int* __restrict__ sel,
    int layer, int task0, size_t tsi, size_t tso)
{
    const int y0  = (blockIdx.x >> 1) * 4;
    const int px0 = (blockIdx.x & 1) * 64;
    const int b   = blockIdx.y;
    const int tz  = blockIdx.z;
    const int t   = task0 + tz;

    const _Float16* inp = in + (size_t)tz * tsi + (size_t)b * (HH * WW * CC);
    _Float16* outp      = out + (size_t)tz * tso + (size_t)b * (HH * WW * CC);
    const int tl = t * LL + layer;
    const _Float16* Wt = W3 + (size_t)tl * 36864;

    const int tid  = threadIdx.x;
    const int lane = tid & 63;
    const int w    = tid >> 6;        // wave = output row within block
    const int n    = lane & 31;
    const int ksub = lane >> 5;

    __shared__ __align__(16) _Float16 lds[6 * 66 * PADH]; // 31,680 B

    floatx16 acc[2][2];
#pragma unroll
    for (int o = 0; o < 2; ++o)
#pragma unroll
        for (int j = 0; j < 2; ++j)
#pragma unroll
            for (int i = 0; i < 16; ++i) acc[o][j][i] = 0.f;

    half8 a_cur[4], a_nxt[4];   // [o*2+il]

    // a-frag: contiguous 1 KB wave-load
#define WFRAG(c, tap, o, il) \
    (*(const half8*)(Wt + ((((size_t)(tap) * 2 + (c)) * 2 + (il)) * 2 + (o)) * 512 + lane * 8))

#pragma unroll
    for (int o = 0; o < 2; ++o)
#pragma unroll
        for (int il = 0; il < 2; ++il) a_cur[o * 2 + il] = WFRAG(0, 0, o, il);

    for (int c = 0; c < 2; ++c) {
        if (c) __syncthreads();   // all reads of previous chunk done
        // ---- stage input chunk: 6 rows x 66 px x 32 ch ----
        for (int i = tid; i < 1584; i += 256) {
            int r   = i / 264;
            int rem = i - r * 264;
            int px  = rem >> 2;
            int c8  = rem & 3;
            int gy = y0 - 1 + r;
            int gx = px0 - 1 + px;
            half8 v = {};
            if ((unsigned)gy < HH && (unsigned)gx < WW)
                v = *(const half8*)(inp + ((size_t)gy * WW + gx) * CC + c * 32 + c8 * 8);
            *(half8*)&lds[(r * 66 + px) * PADH + c8 * 8] = v;
        }
        __syncthreads();

#pragma unroll
        for (int tap = 0; tap < 9; ++tap) {
            // prefetch next (c,tap) weight frags
            int nc   = (tap == 8) ? c + 1 : c;
            int ntap = (tap == 8) ? 0 : tap + 1;
            if (nc < 2) {
#pragma unroll
                for (int o = 0; o < 2; ++o)
#pragma unroll
                    for (int il = 0; il < 2; ++il) a_nxt[o * 2 + il] = WFRAG(nc, ntap, o, il);
            }
            const int dy = tap / 3;
            const int dx = tap - dy * 3;
            const _Float16* lbase = &lds[((w + dy) * 66 + dx) * PADH];
#pragma unroll
            for (int il = 0; il < 2; ++il) {
                const int koff = (il * 2 + ksub) * 8;
                half8 b0 = *(const half8*)(lbase + (n) * PADH + koff);
                half8 b1 = *(const half8*)(lbase + (32 + n) * PADH + koff);
                acc[0][0] = __builtin_amdgcn_mfma_f32_32x32x16_f16(a_cur[il],     b0, acc[0][0], 0, 0, 0);
                acc[0][1] = __builtin_amdgcn_mfma_f32_32x32x16_f16(a_cur[il],     b1, acc[0][1], 0, 0, 0);
                acc[1][0] = __builtin_amdgcn_mfma_f32_32x32x16_f16(a_cur[2 + il], b0, acc[1][0], 0, 0, 0);
                acc[1][1] = __builtin_amdgcn_mfma_f32_32x32x16_f16(a_cur[2 + il], b1, acc[1][1], 0, 0, 0);
            }
#pragma unroll
            for (int q = 0; q < 4; ++q) a_cur[q] = a_nxt[q];
        }
    }
#undef WFRAG

    // ---- epilogue: bias + ReLU -> NHWC f16 ----
    int m = sel[t * LL + layer];
    m = __builtin_amdgcn_readfirstlane(m);
    const float* Bp = enc_b + ((size_t)layer * MM + m) * CC;
    _Float16* orow = outp + (size_t)(y0 + w) * WW * CC;
#pragma unroll
    for (int o = 0; o < 2; ++o)
#pragma unroll
        for (int j = 0; j < 2; ++j) {
            int px = px0 + j * 32 + n;
            _Float16* po = orow + (size_t)px * CC;
#pragma unroll
            for (int rg = 0; rg < 4; ++rg) {
                int oc = o * 32 + 4 * ksub + 8 * rg;
                half4 h;
#pragma unroll
                for (int k = 0; k < 4; ++k)
                    h[k] = (_Float16)fmaxf(acc[o][j][rg * 4 + k] + Bp[oc + k], 0.f);
                *(half4*)(po + oc) = h;
            }
        }
}

// ---------------------------------------------------------------------------
// Decoder: 1x1 conv 64 -> 3 (+bias), L2-normalize for task 2. NHWC f16 input.
// ---------------------------------------------------------------------------
__global__ __launch_bounds__(256) void decoder_kernel(
    const _Float16* __restrict__ in, // NHWC f16, per-task stride ts halves
    size_t ts,
    const float* __restrict__ dec_w, // [T][3][64]
    const float* __restrict__ dec_b, // [T][3]
    float* __restrict__ out,         // [T][B][3][H][W]
    int task0, int ntask)
{
    const int HW = HH * WW;
    int gid = blockIdx.x * 256 + threadIdx.x;
    if (gid >= ntask * BB * HW) return;
    int tz = gid / (BB * HW);
    int rem = gid - tz * (BB * HW);
    int b = rem / HW;
    int px = rem - b * HW;
    int t = task0 + tz;

    const _Float16* hp = in + (size_t)tz * ts + ((size_t)b * HW + px) * CC;
    const float* w = dec_w + (size_t)t * 3 * CC;

    float a0 = dec_b[t * 3 + 0];
    float a1 = dec_b[t * 3 + 1];
    float a2 = dec_b[t * 3 + 2];
#pragma unroll
    for (int cc = 0; cc < CC; cc += 8) {
        half8 h = *(const half8*)(hp + cc);
#pragma unroll
        for (int k = 0; k < 8; ++k) {
            float v = (float)h[k];
            a0 += v * w[cc + k];
            a1 += v * w[CC + cc + k];
            a2 += v * w[2 * CC + cc + k];
        }
    }
    if (t == 2) {
        float r = 1.0f / sqrtf(a0 * a0 + a1 * a1 + a2 * a2);
        a0 *= r; a1 *= r; a2 *= r;
    }
    float* ob = out + ((size_t)t * BB + b) * 3 * HW + px;
    ob[0]      = a0;
    ob[HW]     = a1;
    ob[2 * HW] = a2;
}

extern "C" void kernel_launch(void* const* d_in, const int* in_sizes, int n_in,
                              void* d_out, int out_size, void* d_ws, size_t ws_size,
                              hipStream_t stream) {
    const float* x      = (const float*)d_in[0];
    const float* alpha0 = (const float*)d_in[1];
    const float* alphas = (const float*)d_in[2];
    const float* g0     = (const float*)d_in[3];
    const float* gs     = (const float*)d_in[4];
    const float* enc_w  = (const float*)d_in[5];
    const float* enc_b  = (const float*)d_in[6];
    const float* dec_w  = (const float*)d_in[7];
    const float* dec_b  = (const float*)d_in[8];
    float* out = (float*)d_out;

    const size_t ACT = (size_t)BB * HH * WW * CC;      // halves per activation buffer
    char* pw = (char*)d_ws;
    int* sel = (int*)pw;                 pw += 1024;
    _Float16* W3 = (_Float16*)pw;        pw += (size_t)12 * 36864 * 2;
    _Float16* act0 = (_Float16*)pw;      pw += ACT * 2;
    _Float16* bufs = (_Float16*)pw;
    size_t base = (size_t)(pw - (char*)d_ws);
    bool fused = ws_size >= base + 6 * ACT * 2;

    routing_kernel<<<1, 64, 0, stream>>>(alpha0, alphas, g0, gs, sel);
    prep_weights<<<dim3(36, 12), 256, 0, stream>>>(enc_w, sel, W3);
    to_nhwc<<<dim3(2, HH, BB), 256, 0, stream>>>(x, act0);

    if (fused) {
        _Float16* A = bufs;        // task stride 2*ACT
        _Float16* B = bufs + ACT;  // task stride 2*ACT
        size_t ts = 2 * ACT;
        conv3x3_mfma<<<dim3(64, BB, 3), 256, 0, stream>>>(act0, A, W3, enc_b, sel, 0, 0, 0,  ts);
        conv3x3_mfma<<<dim3(64, BB, 3), 256, 0, stream>>>(A,    B, W3, enc_b, sel, 1, 0, ts, ts);
        conv3x3_mfma<<<dim3(64, BB, 3), 256, 0, stream>>>(B,    A, W3, enc_b, sel, 2, 0, ts, ts);
        conv3x3_mfma<<<dim3(64, BB, 3), 256, 0, stream>>>(A,    B, W3, enc_b, sel, 3, 0, ts, ts);
        decoder_kernel<<<(3 * BB * HH * WW + 255) / 256, 256, 0, stream>>>(
            B, ts, dec_w, dec_b, out, 0, 3);
    } else {
        _Float16* A = bufs;
        _Float16* B = bufs + ACT;
        for (int t = 0; t < TT; ++t) {
            conv3x3_mfma<<<dim3(64, BB, 1), 256, 0, stream>>>(act0, A, W3, enc_b, sel, 0, t, 0, 0);
            conv3x3_mfma<<<dim3(64, BB, 1), 256, 0, stream>>>(A,    B, W3, enc_b, sel, 1, t, 0, 0);
            conv3x3_mfma<<<dim3(64, BB, 1), 256, 0, stream>>>(B,    A, W3, enc_b, sel, 2, t, 0, 0);
            conv3x3_mfma<<<dim3(64, BB, 1), 256, 0, stream>>>(A,    B, W3, enc_b, sel, 3, t, 0, 0);
            decoder_kernel<<<(BB * HH * WW + 255) / 256, 256, 0, stream>>>(
                B, 0, dec_w, dec_b, out, t, 1);
        }
    }
}